// Round 1
// baseline (467.121 us; speedup 1.0000x reference)
//
#include <hip/hip_runtime.h>
#include <hip/hip_bf16.h>

// ArcFace fused: cos = emb @ (w/||w||), margin on target, softmax over batch axis.
// N=512 rows, D=512, C=100000 cols, S=1.
// Kernel 1: emb (f32, already row-normalized) -> bf16 A-fragments in d_ws (512 KB).
// Kernel 2: per block: 64 columns x all 512 rows; bf16 MFMA GEMM with fused
//           w-column norms, margin transform, and in-block column softmax.

static constexpr int DIM    = 512;     // D (= K of the GEMM)
static constexpr int NROWS  = 512;     // N (batch; = M of the GEMM)
static constexpr int NCLS   = 100000;  // C
static constexpr int BC     = 64;      // columns per block
static constexpr int BK     = 32;      // K per step (one MFMA K)
static constexpr int NSTEP  = DIM / BK;        // 16
static constexpr int MT     = NROWS / 16;      // 32 M-tiles
static constexpr int NBLK   = (NCLS + BC - 1) / BC;  // 1563

static constexpr float COS_M = 0.87758256189037271611f;  // cos(0.5)
static constexpr float SIN_M = 0.47942553860420300027f;  // sin(0.5)
static constexpr float SCALE = 64.0f;

typedef __attribute__((ext_vector_type(8))) short bf16x8;
typedef __attribute__((ext_vector_type(4))) float f32x4;

__device__ __forceinline__ unsigned short f2bf(float f) {
  union { float f; unsigned u; } v; v.f = f;
  unsigned u = v.u;
  return (unsigned short)((u + 0x7FFFu + ((u >> 16) & 1u)) >> 16);
}

// ---------------------------------------------------------------------------
// Prep: emb [512][512] f32 -> bf16 A-fragments.
// afrag[((ks*MT + mt)*64 + lane)*8 + j] = bf16(emb[mt*16 + (lane&15)][ks*32 + (lane>>4)*8 + j])
// so the main kernel's lane reads its 16x32-tile A fragment as one 16B load.
// ---------------------------------------------------------------------------
__global__ void prep_afrag(const float* __restrict__ emb,
                           unsigned short* __restrict__ afrag) {
  const int idx = blockIdx.x * blockDim.x + threadIdx.x;  // 0..32767
  const int l  = idx & 63;
  const int mt = (idx >> 6) & 31;
  const int ks = idx >> 11;            // 0..15
  const int row = mt * 16 + (l & 15);
  const int k0  = ks * 32 + (l >> 4) * 8;

  unsigned short t[8];
#pragma unroll
  for (int j = 0; j < 8; ++j) t[j] = f2bf(emb[row * DIM + k0 + j]);

  uint4 v;
  v.x = (unsigned)t[0] | ((unsigned)t[1] << 16);
  v.y = (unsigned)t[2] | ((unsigned)t[3] << 16);
  v.z = (unsigned)t[4] | ((unsigned)t[5] << 16);
  v.w = (unsigned)t[6] | ((unsigned)t[7] << 16);
  *reinterpret_cast<uint4*>(&afrag[(size_t)idx * 8]) = v;
}

// ---------------------------------------------------------------------------
// Main fused kernel. 512 threads = 8 waves. Wave w owns rows [w*64, w*64+64)
// (4 M-tiles) x all 64 block columns (4 N-tiles) -> acc[4][4] f32x4.
// ---------------------------------------------------------------------------
__global__ __launch_bounds__(512)
void arcface_main(const float* __restrict__ w,
                  const float* __restrict__ tgt,
                  const unsigned short* __restrict__ afrag,
                  float* __restrict__ out) {
  __shared__ alignas(16) unsigned short Blds[BC][BK];  // [col][k] bf16, 4 KB
  __shared__ float red[8][BC];
  __shared__ float colv[BC];
  __shared__ float norm2[BC];

  const int tid = threadIdx.x;
  const int wv  = tid >> 6;        // wave 0..7
  const int l   = tid & 63;
  const int lh  = l >> 4;          // 0..3
  const int ll  = l & 15;
  const int c0  = blockIdx.x * BC;

  // staging role: thread stages k = sk (0..31), cols sc..sc+3
  const int sk = tid >> 4;
  const int sc = (tid & 15) * 4;

  f32x4 acc[4][4] = {};
  float nrm[4] = {0.f, 0.f, 0.f, 0.f};

  for (int ks = 0; ks < NSTEP; ++ks) {
    __syncthreads();  // protect Blds from previous iteration's readers
    {
      const int k  = ks * BK + sk;
      const int cg = c0 + sc;
      float x0 = 0.f, x1 = 0.f, x2 = 0.f, x3 = 0.f;
      if (cg + 3 < NCLS) {
        const float4 v = *reinterpret_cast<const float4*>(&w[(size_t)k * NCLS + cg]);
        x0 = v.x; x1 = v.y; x2 = v.z; x3 = v.w;
      } else {
        if (cg + 0 < NCLS) x0 = w[(size_t)k * NCLS + cg + 0];
        if (cg + 1 < NCLS) x1 = w[(size_t)k * NCLS + cg + 1];
        if (cg + 2 < NCLS) x2 = w[(size_t)k * NCLS + cg + 2];
        if (cg + 3 < NCLS) x3 = w[(size_t)k * NCLS + cg + 3];
      }
      nrm[0] += x0 * x0; nrm[1] += x1 * x1; nrm[2] += x2 * x2; nrm[3] += x3 * x3;
      Blds[sc + 0][sk] = f2bf(x0);
      Blds[sc + 1][sk] = f2bf(x1);
      Blds[sc + 2][sk] = f2bf(x2);
      Blds[sc + 3][sk] = f2bf(x3);
    }
    __syncthreads();

    bf16x8 a[4], b[4];
#pragma unroll
    for (int i = 0; i < 4; ++i) {
      const int mt = wv * 4 + i;
      a[i] = *reinterpret_cast<const bf16x8*>(&afrag[((size_t)(ks * MT + mt) * 64 + l) * 8]);
    }
#pragma unroll
    for (int j = 0; j < 4; ++j)
      b[j] = *reinterpret_cast<const bf16x8*>(&Blds[j * 16 + ll][lh * 8]);
#pragma unroll
    for (int i = 0; i < 4; ++i)
#pragma unroll
      for (int j = 0; j < 4; ++j)
        acc[i][j] = __builtin_amdgcn_mfma_f32_16x16x32_bf16(a[i], b[j], acc[i][j], 0, 0, 0);
  }

  // ---- w column norms: deterministic reduce (shfl over sk-groups, LDS over waves)
#pragma unroll
  for (int i = 0; i < 4; ++i) {
    nrm[i] += __shfl_xor(nrm[i], 16, 64);
    nrm[i] += __shfl_xor(nrm[i], 32, 64);
  }
  if (l < 16) {
#pragma unroll
    for (int i = 0; i < 4; ++i) red[wv][l * 4 + i] = nrm[i];
  }
  __syncthreads();
  if (tid < BC) {
    float s = 0.f;
#pragma unroll
    for (int v2 = 0; v2 < 8; ++v2) s += red[v2][tid];
    norm2[tid] = s;
  }
  __syncthreads();

  // ---- logits: cos -> clip -> margin (no acos/cos needed) -> *64; track col max
  float rn[4], mx[4];
#pragma unroll
  for (int j = 0; j < 4; ++j) {
    rn[j] = rsqrtf(fmaxf(norm2[j * 16 + ll], 1e-20f));
    mx[j] = -3.4e38f;
  }
#pragma unroll
  for (int j = 0; j < 4; ++j) {
    const int cj = c0 + j * 16 + ll;
    const bool ok = cj < NCLS;
#pragma unroll
    for (int i = 0; i < 4; ++i) {
#pragma unroll
      for (int q = 0; q < 4; ++q) {
        const int row = wv * 64 + i * 16 + lh * 4 + q;
        float cosv = acc[i][j][q] * rn[j];
        cosv = fminf(fmaxf(cosv, -1.f), 1.f);
        const float t = ok ? tgt[(size_t)row * NCLS + cj] : 0.f;
        float lg;
        if (t > 0.5f) {
          const float s = sqrtf(fmaxf(1.f - cosv * cosv, 0.f));
          lg = cosv * COS_M - s * SIN_M;
        } else {
          lg = cosv;
        }
        lg *= SCALE;
        acc[i][j][q] = lg;
        mx[j] = fmaxf(mx[j], lg);
      }
    }
  }

  // ---- softmax over the 512 rows of each column (axis=0)
  // reduce max: within wave over row-subgroups (lanes xor 16/32), then across waves
#pragma unroll
  for (int j = 0; j < 4; ++j) {
    mx[j] = fmaxf(mx[j], __shfl_xor(mx[j], 16, 64));
    mx[j] = fmaxf(mx[j], __shfl_xor(mx[j], 32, 64));
  }
  if (l < 16) {
#pragma unroll
    for (int j = 0; j < 4; ++j) red[wv][j * 16 + l] = mx[j];
  }
  __syncthreads();
  if (tid < BC) {
    float m = red[0][tid];
#pragma unroll
    for (int v2 = 1; v2 < 8; ++v2) m = fmaxf(m, red[v2][tid]);
    colv[tid] = m;
  }
  __syncthreads();
  float cmax[4];
#pragma unroll
  for (int j = 0; j < 4; ++j) cmax[j] = colv[j * 16 + ll];

  float sme[4] = {0.f, 0.f, 0.f, 0.f};
#pragma unroll
  for (int j = 0; j < 4; ++j)
#pragma unroll
    for (int i = 0; i < 4; ++i)
#pragma unroll
      for (int q = 0; q < 4; ++q) {
        const float e = __expf(acc[i][j][q] - cmax[j]);
        acc[i][j][q] = e;
        sme[j] += e;
      }
#pragma unroll
  for (int j = 0; j < 4; ++j) {
    sme[j] += __shfl_xor(sme[j], 16, 64);
    sme[j] += __shfl_xor(sme[j], 32, 64);
  }
  if (l < 16) {
#pragma unroll
    for (int j = 0; j < 4; ++j) red[wv][j * 16 + l] = sme[j];
  }
  __syncthreads();
  if (tid < BC) {
    float s = 0.f;
#pragma unroll
    for (int v2 = 0; v2 < 8; ++v2) s += red[v2][tid];
    colv[tid] = s;
  }
  __syncthreads();

  float rs[4];
#pragma unroll
  for (int j = 0; j < 4; ++j) rs[j] = 1.0f / colv[j * 16 + ll];

#pragma unroll
  for (int j = 0; j < 4; ++j) {
    const int cj = c0 + j * 16 + ll;
    if (cj >= NCLS) continue;
#pragma unroll
    for (int i = 0; i < 4; ++i) {
#pragma unroll
      for (int q = 0; q < 4; ++q) {
        const int row = wv * 64 + i * 16 + lh * 4 + q;
        out[(size_t)row * NCLS + cj] = acc[i][j][q] * rs[j];
      }
    }
  }
}

extern "C" void kernel_launch(void* const* d_in, const int* in_sizes, int n_in,
                              void* d_out, int out_size, void* d_ws, size_t ws_size,
                              hipStream_t stream) {
  const float* emb = (const float*)d_in[0];   // [512][512]
  const float* w   = (const float*)d_in[1];   // [512][100000]
  const float* tgt = (const float*)d_in[2];   // [512][100000]
  float* out = (float*)d_out;                 // [512][100000]
  unsigned short* afrag = (unsigned short*)d_ws;  // 512 KB bf16 A-fragments

  prep_afrag<<<64, 512, 0, stream>>>(emb, afrag);
  arcface_main<<<NBLK, 512, 0, stream>>>(w, tgt, afrag, out);
}

// Round 2
// 322.922 us; speedup vs baseline: 1.4465x; 1.4465x over previous
//
#include <hip/hip_runtime.h>
#include <hip/hip_bf16.h>

// ArcFace fused: cos = emb @ (w/||w||), margin on target label, softmax over batch axis.
// N=512 rows, D=512, C=100000 cols, S=1.
// Kernel 1: label_scan  — tgt one-hot [512][100000] -> labels[512] (streaming, full BW).
// Kernel 2: prep_afrag  — emb f32 -> bf16 A-fragments in ws (512 KB, L2-resident).
// Kernel 3: arcface_main — NO LDS / NO barriers in K-loop: B-fragments loaded directly
//           from global (scalar f32, 64B-coalesced per 16-lane group), fused norms via
//           shfl, margin via label compare, in-block column softmax.

static constexpr int DIM    = 512;     // D (= K of the GEMM)
static constexpr int NROWS  = 512;     // N (batch; = M of the GEMM)
static constexpr int NCLS   = 100000;  // C
static constexpr int BC     = 64;      // columns per block
static constexpr int BK     = 32;      // K per step (one MFMA K)
static constexpr int NSTEP  = DIM / BK;        // 16
static constexpr int MT     = NROWS / 16;      // 32 M-tiles
static constexpr int NBLK   = (NCLS + BC - 1) / BC;  // 1563

static constexpr float COS_M = 0.87758256189037271611f;  // cos(0.5)
static constexpr float SIN_M = 0.47942553860420300027f;  // sin(0.5)
static constexpr float SCALE = 64.0f;

typedef __attribute__((ext_vector_type(8))) short bf16x8;
typedef __attribute__((ext_vector_type(4))) float f32x4;

__device__ __forceinline__ unsigned short f2bf(float f) {
  union { float f; unsigned u; } v; v.f = f;
  unsigned u = v.u;
  return (unsigned short)((u + 0x7FFFu + ((u >> 16) & 1u)) >> 16);
}

// ---------------------------------------------------------------------------
// tgt [512][100000] one-hot -> labels[512]. Streaming float4, exactly one 1.0/row.
// ---------------------------------------------------------------------------
__global__ __launch_bounds__(1024)
void label_scan(const float* __restrict__ tgt, int* __restrict__ labels) {
  const int row = blockIdx.x;
  const float4* rp = reinterpret_cast<const float4*>(tgt + (size_t)row * NCLS);
  int found = -1;
  for (int c4 = threadIdx.x; c4 < NCLS / 4; c4 += 1024) {
    const float4 v = rp[c4];
    if (v.x > 0.5f) found = c4 * 4 + 0;
    if (v.y > 0.5f) found = c4 * 4 + 1;
    if (v.z > 0.5f) found = c4 * 4 + 2;
    if (v.w > 0.5f) found = c4 * 4 + 3;
  }
  if (found >= 0) labels[row] = found;   // exactly one writer per row
}

// ---------------------------------------------------------------------------
// emb [512][512] f32 -> bf16 A-fragments:
// afrag[((ks*MT+mt)*64 + lane)*8 + j] = bf16(emb[mt*16 + (lane&15)][ks*32 + (lane>>4)*8 + j])
// ---------------------------------------------------------------------------
__global__ void prep_afrag(const float* __restrict__ emb,
                           unsigned short* __restrict__ afrag) {
  const int idx = blockIdx.x * blockDim.x + threadIdx.x;  // 0..32767
  const int l  = idx & 63;
  const int mt = (idx >> 6) & 31;
  const int ks = idx >> 11;            // 0..15
  const int row = mt * 16 + (l & 15);
  const int k0  = ks * 32 + (l >> 4) * 8;

  unsigned short t[8];
#pragma unroll
  for (int j = 0; j < 8; ++j) t[j] = f2bf(emb[row * DIM + k0 + j]);

  uint4 v;
  v.x = (unsigned)t[0] | ((unsigned)t[1] << 16);
  v.y = (unsigned)t[2] | ((unsigned)t[3] << 16);
  v.z = (unsigned)t[4] | ((unsigned)t[5] << 16);
  v.w = (unsigned)t[6] | ((unsigned)t[7] << 16);
  *reinterpret_cast<uint4*>(&afrag[(size_t)idx * 8]) = v;
}

// ---------------------------------------------------------------------------
// Main fused kernel. 512 threads = 8 waves. Wave wv owns rows [wv*64, wv*64+64)
// (4 M-tiles) x all 64 block columns (4 N-tiles) -> acc[4][4] f32x4.
// K-loop has NO LDS and NO barriers.
// ---------------------------------------------------------------------------
__global__ __launch_bounds__(512)
void arcface_main(const float* __restrict__ w,
                  const int* __restrict__ labels,
                  const unsigned short* __restrict__ afrag,
                  float* __restrict__ out) {
  __shared__ float red[8][BC];
  __shared__ float colv[BC];

  const int tid = threadIdx.x;
  const int wv  = tid >> 6;        // wave 0..7
  const int l   = tid & 63;
  const int lh  = l >> 4;          // 0..3
  const int ll  = l & 15;
  const int c0  = blockIdx.x * BC;

  // per-lane true column ids + clamped load columns (last block: dup col, never stored)
  int cj[4]; size_t ccol[4];
#pragma unroll
  for (int j = 0; j < 4; ++j) {
    cj[j] = c0 + j * 16 + ll;
    ccol[j] = (size_t)(cj[j] < NCLS ? cj[j] : NCLS - 1);
  }

  f32x4 acc[4][4] = {};
  float nrm[4] = {0.f, 0.f, 0.f, 0.f};

  for (int ks = 0; ks < NSTEP; ++ks) {
    // ---- B loads: lane (ll,lh) reads col cj[j], k = ks*32 + lh*8 + e.
    // For fixed (lh,e), 16 ll-lanes read 16 consecutive floats: 64B segments.
    float bx[4][8];
    const size_t rowbase = (size_t)(ks * BK + lh * 8) * NCLS;
#pragma unroll
    for (int j = 0; j < 4; ++j) {
      const float* p = w + rowbase + ccol[j];
#pragma unroll
      for (int e = 0; e < 8; ++e) bx[j][e] = p[(size_t)e * NCLS];
    }

    // ---- A fragments (512KB, shared by all blocks -> L2-resident)
    bf16x8 a[4];
#pragma unroll
    for (int i = 0; i < 4; ++i)
      a[i] = *reinterpret_cast<const bf16x8*>(
          &afrag[((size_t)(ks * MT + wv * 4 + i) * 64 + l) * 8]);

    // ---- norms (f32) + pack to bf16
    bf16x8 b[4];
#pragma unroll
    for (int j = 0; j < 4; ++j) {
#pragma unroll
      for (int e = 0; e < 8; ++e) nrm[j] += bx[j][e] * bx[j][e];
#pragma unroll
      for (int e = 0; e < 8; ++e) b[j][e] = (short)f2bf(bx[j][e]);
    }

#pragma unroll
    for (int i = 0; i < 4; ++i)
#pragma unroll
      for (int j = 0; j < 4; ++j)
        acc[i][j] = __builtin_amdgcn_mfma_f32_16x16x32_bf16(a[i], b[j], acc[i][j], 0, 0, 0);
  }

  // ---- finish column norms: lanes sharing a column differ in lh (xor 16/32)
  float rn[4];
#pragma unroll
  for (int j = 0; j < 4; ++j) {
    nrm[j] += __shfl_xor(nrm[j], 16, 64);
    nrm[j] += __shfl_xor(nrm[j], 32, 64);
    rn[j] = rsqrtf(fmaxf(nrm[j], 1e-20f));
  }

  // ---- labels for my 16 rows (2KB hot region, L2 hits)
  int lab[4][4];
#pragma unroll
  for (int i = 0; i < 4; ++i)
#pragma unroll
    for (int q = 0; q < 4; ++q)
      lab[i][q] = labels[wv * 64 + i * 16 + lh * 4 + q];

  // ---- logits: cos -> clip -> margin (target position only) -> *64; track col max
  float mx[4];
#pragma unroll
  for (int j = 0; j < 4; ++j) mx[j] = -3.4e38f;
#pragma unroll
  for (int j = 0; j < 4; ++j) {
#pragma unroll
    for (int i = 0; i < 4; ++i) {
#pragma unroll
      for (int q = 0; q < 4; ++q) {
        float cosv = acc[i][j][q] * rn[j];
        cosv = fminf(fmaxf(cosv, -1.f), 1.f);
        float lg;
        if (lab[i][q] == cj[j]) {
          const float s = sqrtf(fmaxf(1.f - cosv * cosv, 0.f));
          lg = cosv * COS_M - s * SIN_M;
        } else {
          lg = cosv;
        }
        lg *= SCALE;
        acc[i][j][q] = lg;
        mx[j] = fmaxf(mx[j], lg);
      }
    }
  }

  // ---- softmax over the 512 rows of each column (axis=0)
#pragma unroll
  for (int j = 0; j < 4; ++j) {
    mx[j] = fmaxf(mx[j], __shfl_xor(mx[j], 16, 64));
    mx[j] = fmaxf(mx[j], __shfl_xor(mx[j], 32, 64));
  }
  if (l < 16) {
#pragma unroll
    for (int j = 0; j < 4; ++j) red[wv][j * 16 + l] = mx[j];
  }
  __syncthreads();
  if (tid < BC) {
    float m = red[0][tid];
#pragma unroll
    for (int v2 = 1; v2 < 8; ++v2) m = fmaxf(m, red[v2][tid]);
    colv[tid] = m;
  }
  __syncthreads();
  float cmax[4];
#pragma unroll
  for (int j = 0; j < 4; ++j) cmax[j] = colv[j * 16 + ll];

  float sme[4] = {0.f, 0.f, 0.f, 0.f};
#pragma unroll
  for (int j = 0; j < 4; ++j)
#pragma unroll
    for (int i = 0; i < 4; ++i)
#pragma unroll
      for (int q = 0; q < 4; ++q) {
        const float e = __expf(acc[i][j][q] - cmax[j]);
        acc[i][j][q] = e;
        sme[j] += e;
      }
#pragma unroll
  for (int j = 0; j < 4; ++j) {
    sme[j] += __shfl_xor(sme[j], 16, 64);
    sme[j] += __shfl_xor(sme[j], 32, 64);
  }
  __syncthreads();  // red reuse
  if (l < 16) {
#pragma unroll
    for (int j = 0; j < 4; ++j) red[wv][j * 16 + l] = sme[j];
  }
  __syncthreads();
  if (tid < BC) {
    float s = 0.f;
#pragma unroll
    for (int v2 = 0; v2 < 8; ++v2) s += red[v2][tid];
    colv[tid] = s;
  }
  __syncthreads();

  float rs[4];
#pragma unroll
  for (int j = 0; j < 4; ++j) rs[j] = 1.0f / colv[j * 16 + ll];

#pragma unroll
  for (int j = 0; j < 4; ++j) {
    if (cj[j] >= NCLS) continue;
#pragma unroll
    for (int i = 0; i < 4; ++i) {
#pragma unroll
      for (int q = 0; q < 4; ++q) {
        const int row = wv * 64 + i * 16 + lh * 4 + q;
        out[(size_t)row * NCLS + cj[j]] = acc[i][j][q] * rs[j];
      }
    }
  }
}

extern "C" void kernel_launch(void* const* d_in, const int* in_sizes, int n_in,
                              void* d_out, int out_size, void* d_ws, size_t ws_size,
                              hipStream_t stream) {
  const float* emb = (const float*)d_in[0];   // [512][512]
  const float* w   = (const float*)d_in[1];   // [512][100000]
  const float* tgt = (const float*)d_in[2];   // [512][100000]
  float* out = (float*)d_out;                 // [512][100000]

  int* labels = (int*)d_ws;                                        // 2 KB
  unsigned short* afrag = (unsigned short*)((char*)d_ws + 4096);   // 512 KB

  label_scan<<<NROWS, 1024, 0, stream>>>(tgt, labels);
  prep_afrag<<<64, 512, 0, stream>>>(emb, afrag);
  arcface_main<<<NBLK, 512, 0, stream>>>(w, labels, afrag, out);
}